// Round 12
// baseline (92.875 us; speedup 1.0000x reference)
//
#include <hip/hip_runtime.h>

#define RELN 8
#define DIMN 256
#define BN_  8
#define SN   512
#define TN   512

typedef __attribute__((ext_vector_type(8))) short bf16x8;   // 8 bf16 payloads
typedef __attribute__((ext_vector_type(4))) short bf16x4;
typedef __attribute__((ext_vector_type(4))) float f32x4;

__device__ __forceinline__ unsigned short f2bf(float f) {
    union { float f; unsigned u; } x; x.f = f;
    return (unsigned short)((x.u + 0x7FFFu + ((x.u >> 16) & 1u)) >> 16);  // RNE
}
__device__ __forceinline__ float bf2f(unsigned short h) {
    union { unsigned u; float f; } x; x.u = (unsigned)h << 16; return x.f;
}

// ---------------------------------------------------------------------------
// bf16 MFMA GEMM, B^T layout (A: MxK row-major, B: NxK row-major).
// 128x128 tile, template BK, 4 waves x 64x64 quadrant (frags of 16x16x32).
// 2-phase double-buffered staging; global_load_lds width=16, linear LDS.
// MODE 1/2/3: BK=32 -> LDS 32 KB -> 5 blocks/CU co-residency (the per-step
// vmcnt(0)+barrier drain is hidden by other resident blocks' MFMA, m114;
// round-9 measured -12us going 2->4 blocks; this round tests 4->5).
// MODE 4:     BK=64, 2 blocks/CU (round-11 measured: BK=32/4-blocks is
// WORSE for the K=1024 split-K — doubled barrier count loses).
// Plain 3-D grids: data is L3-resident, XCD swizzle out-of-regime (round 10).
// MODE 1: scores = src_bf @ WscoreT[r]                     (z=r,      bf16)
// MODE 2: w~ = exp(mask(scores @ tar_bf^T)/16)             (z=r*8+b,  bf16)
//         + column-sum atomicAdd into L[rb][t]  (no-max-sub softmax: logits
//         bounded ~|6| by construction, exp never overflows f32)
// MODE 3: relT = (tar_bf @ WembT[r]) / L[rb][t], transposed 2-pass LDS
//         bounce (pitch 136, conflict-free) -> coalesced 16B stores
// MODE 4: split-K over fused (r,t): outp4[z] = sum w~*relT partials
//         (z=0..3, K=1024, f32 direct stores)
// ---------------------------------------------------------------------------
#define TBN 128
#define BP12 128   // MODE1/2 bounce pitch (shorts): 128x128 = 32 KB = Sh size
#define BP3  136   // MODE3 transposed bounce pitch: 2-way max on both sides

template<int MODE, int BK>
__global__ __launch_bounds__(256, (MODE == 4 ? 2 : 5))
void gemm_bt(const unsigned short* __restrict__ A,
             const unsigned short* __restrict__ B,
             void* __restrict__ C, int K,
             int lda, int ldb,
             const float* __restrict__ msrc,
             const float* __restrict__ mtar,
             float* __restrict__ Lsum)
{
    __shared__ unsigned short Sh[2][(128 + TBN) * BK];
    const int tid  = threadIdx.x;
    const int lane = tid & 63;
    const int wv   = tid >> 6;
    const int wr   = (wv >> 1) * 64;
    const int wc   = (wv & 1) * 64;
    const int m0   = blockIdx.x * 128;
    const int n0   = blockIdx.y * TBN;
    const int z    = blockIdx.z;
    const int bblk = m0 >> 9;        // MODE 2/3/4: batch b of this m-tile
    const int rz   = z * 2;          // MODE 4: first r of this z's pair

    const unsigned short* Ab = A;
    const unsigned short* Bb = B;
    if (MODE == 1)      { Bb += (size_t)z * DIMN * DIMN; }
    else if (MODE == 2) { Ab += (size_t)z * SN * DIMN; Bb += (size_t)(z & 7) * TN * DIMN; }
    else if (MODE == 3) { Bb += (size_t)z * DIMN * DIMN; }

    // stage one 128xBK A-tile + 128xBK B-tile into Sh[buf]; LDS dest linear
    // (wave base + lane*16B HW scatter), global src matches elementwise.
    constexpr int CPR = BK / 8;            // 16B chunks per row
    constexpr int NP  = 128 * CPR / 256;   // passes per operand
    auto stage = [&](int buf, int kt) {
        unsigned short* Abase = Sh[buf];
        unsigned short* Bbase = Sh[buf] + 128 * BK;
        #pragma unroll
        for (int p = 0; p < NP; ++p) {
            int idx8 = p * 256 + tid;
            int row  = idx8 / CPR;
            int col  = (idx8 % CPR) * 8;
            size_t aoff, boff;
            if (MODE == 4) {
                int r = rz + (kt >> 9);        // fused k = r_local*512 + t
                int t = (kt & 511) + col;      // BK | 512: never crosses r
                aoff = ((size_t)((r*BN_ + bblk)*SN + ((m0 + row) & 511)))*TN + t;
                boff = ((size_t)((r*BN_ + bblk)*DIMN + (n0 + row)))*TN + t;
            } else {
                aoff = (size_t)(m0 + row)*lda + kt + col;
                boff = (size_t)(n0 + row)*ldb + kt + col;
            }
            __builtin_amdgcn_global_load_lds(
                (const __attribute__((address_space(1))) unsigned int*)&Ab[aoff],
                (__attribute__((address_space(3))) unsigned int*)
                    &Abase[p*2048 + wv*512], 16, 0, 0);
            __builtin_amdgcn_global_load_lds(
                (const __attribute__((address_space(1))) unsigned int*)&Bb[boff],
                (__attribute__((address_space(3))) unsigned int*)
                    &Bbase[p*2048 + wv*512], 16, 0, 0);
        }
    };

    f32x4 acc[4][4] = {};
    const int nsteps = K / BK;
    stage(0, 0);
    int cur = 0;
    for (int s = 0; s < nsteps; ++s) {
        // drains vmcnt(0): buf[cur] ready; all waves done reading buf[cur^1]
        __syncthreads();
        if (s + 1 < nsteps) stage(cur ^ 1, (s + 1) * BK);   // in flight over MFMA
        const unsigned short* As = Sh[cur];
        const unsigned short* Bs = Sh[cur] + 128 * BK;
        #pragma unroll
        for (int kk = 0; kk < BK / 32; ++kk) {
            const int ko = kk*32 + (lane >> 4) * 8;
            bf16x8 af[4], bfv[4];
            #pragma unroll
            for (int i = 0; i < 4; ++i)
                af[i] = *(const bf16x8*)&As[(wr + i*16 + (lane & 15))*BK + ko];
            #pragma unroll
            for (int j = 0; j < 4; ++j)
                bfv[j] = *(const bf16x8*)&Bs[(wc + j*16 + (lane & 15))*BK + ko];
            #pragma unroll
            for (int i = 0; i < 4; ++i) {
                #pragma unroll
                for (int j = 0; j < 4; ++j)
                    acc[i][j] = __builtin_amdgcn_mfma_f32_16x16x32_bf16(af[i], bfv[j], acc[i][j], 0, 0, 0);
            }
        }
        cur ^= 1;
    }

    // C/D frag mapping (m89-verified): col = lane&15, row = (lane>>4)*4 + reg
    const int r0 = (lane >> 4) * 4;
    const int cl = lane & 15;
    unsigned short* tile = &Sh[0][0];   // bounce space (32 KB at BK=32)

    if (MODE == 2) {
        unsigned short* Cp = (unsigned short*)C + (size_t)z * SN * TN;
        const int b = z & 7;
        float tm[4];
        #pragma unroll
        for (int j = 0; j < 4; ++j) tm[j] = mtar[b*TN + n0 + wc + j*16 + cl];
        float colsum[4] = {0.f, 0.f, 0.f, 0.f};
        __syncthreads();   // staging fully consumed; safe to reuse Sh as bounce
        #pragma unroll
        for (int i = 0; i < 4; ++i) {
            int rowl = wr + i*16 + r0;
            float sm[4];
            #pragma unroll
            for (int q = 0; q < 4; ++q) sm[q] = msrc[b*SN + m0 + rowl + q];
            #pragma unroll
            for (int j = 0; j < 4; ++j) {
                int coll = wc + j*16 + cl;
                #pragma unroll
                for (int q = 0; q < 4; ++q) {
                    float v = (acc[i][j][q] + (1.f - sm[q]*tm[j]) * -1e10f) * 0.0625f;
                    float e = __expf(v);
                    tile[(rowl + q)*BP12 + coll] = f2bf(e);
                    colsum[j] += e;
                }
            }
        }
        // reduce the 4 row-groups (lane>>4) holding the same column, then atomic
        #pragma unroll
        for (int j = 0; j < 4; ++j) {
            float v = colsum[j];
            v += __shfl_xor(v, 16, 64);
            v += __shfl_xor(v, 32, 64);
            if (lane < 16)
                atomicAdd(&Lsum[(size_t)z*TN + n0 + wc + j*16 + cl], v);
        }
        __syncthreads();
        #pragma unroll
        for (int p = 0; p < 8; ++p) {      // 128 rows x 16 chunks of 16 B
            int chunk = p * 256 + tid;
            int row = chunk >> 4, col = (chunk & 15) * 8;
            bf16x8 v = *(const bf16x8*)&tile[row*BP12 + col];
            *(bf16x8*)&Cp[(size_t)(m0 + row)*TN + n0 + col] = v;
        }
    } else if (MODE == 1) {
        unsigned short* Cp = (unsigned short*)C + (size_t)z * (BN_*SN) * DIMN;
        __syncthreads();
        #pragma unroll
        for (int i = 0; i < 4; ++i) {
            int rowl = wr + i*16 + r0;
            #pragma unroll
            for (int j = 0; j < 4; ++j) {
                int coll = wc + j*16 + cl;
                #pragma unroll
                for (int q = 0; q < 4; ++q)
                    tile[(rowl + q)*BP12 + coll] = f2bf(acc[i][j][q]);
            }
        }
        __syncthreads();
        #pragma unroll
        for (int p = 0; p < 8; ++p) {
            int chunk = p * 256 + tid;
            int row = chunk >> 4, col = (chunk & 15) * 8;
            bf16x8 v = *(const bf16x8*)&tile[row*BP12 + col];
            *(bf16x8*)&Cp[(size_t)(m0 + row)*DIMN + n0 + col] = v;
        }
    } else if (MODE == 3) {
        // transposed 2-pass bounce: tile[e_local][t_local] (64 e-rows per
        // pass, pitch 136 -> 2-way max) then coalesced 16B stores of
        // relT[(z*8+b)*256 + e][t]
        unsigned short* Cp = (unsigned short*)C;
        const int t_base = m0 & 511;
        #pragma unroll
        for (int h = 0; h < 2; ++h) {
            __syncthreads();
            if ((wv & 1) == h) {           // waves owning e in [h*64,(h+1)*64)
                #pragma unroll
                for (int i = 0; i < 4; ++i) {
                    int tl0  = wr + i*16 + r0;          // 4 consecutive t (q)
                    float4 Lv = *(const float4*)
                        &Lsum[((size_t)(z*BN_ + bblk))*TN + t_base + tl0];
                    float inv0 = 1.f / Lv.x, inv1 = 1.f / Lv.y,
                          inv2 = 1.f / Lv.z, inv3 = 1.f / Lv.w;
                    #pragma unroll
                    for (int j = 0; j < 4; ++j) {
                        int el = wc + j*16 + cl - h*64;
                        bf16x4 v;
                        v[0] = (short)f2bf(acc[i][j][0] * inv0);
                        v[1] = (short)f2bf(acc[i][j][1] * inv1);
                        v[2] = (short)f2bf(acc[i][j][2] * inv2);
                        v[3] = (short)f2bf(acc[i][j][3] * inv3);
                        *(bf16x4*)&tile[el*BP3 + tl0] = v;
                    }
                }
            }
            __syncthreads();
            #pragma unroll
            for (int p = 0; p < 4; ++p) {  // 64 e-rows x 16 chunks of 16 B
                int chunk = p * 256 + tid;
                int er = chunk >> 4, tc = (chunk & 15) * 8;
                bf16x8 v = *(const bf16x8*)&tile[er*BP3 + tc];
                *(bf16x8*)&Cp[((size_t)(z*BN_ + bblk)*DIMN + n0 + h*64 + er)*TN
                              + t_base + tc] = v;
            }
        }
    } else {
        // per-z partials, plain stores (16 lanes x 4B = 64B contiguous)
        float* Cp = (float*)C + (size_t)z * (BN_*SN) * DIMN;
        #pragma unroll
        for (int i = 0; i < 4; ++i) {
            int row = m0 + wr + i*16 + r0;
            #pragma unroll
            for (int j = 0; j < 4; ++j) {
                int col = n0 + wc + j*16 + cl;
                #pragma unroll
                for (int q = 0; q < 4; ++q)
                    Cp[(size_t)(row + q)*DIMN + col] = acc[i][j][q];
            }
        }
    }
}

// out = (1/sqrt(8)) * sum_{z<4} part[z]  (streaming, fully overwrites d_out)
__global__ void reduce4_kernel(const float* __restrict__ part,
                               float* __restrict__ out, int n4)
{
    int i = blockIdx.x * 256 + threadIdx.x;
    if (i < n4) {
        float4 s = {0.f, 0.f, 0.f, 0.f};
        #pragma unroll
        for (int r = 0; r < 4; ++r) {
            float4 v = *(const float4*)&part[(size_t)r*(BN_*SN*DIMN) + i*4];
            s.x += v.x; s.y += v.y; s.z += v.z; s.w += v.w;
        }
        const float k = 0.35355339059327373f;
        float4 o = {s.x*k, s.y*k, s.z*k, s.w*k};
        *(float4*)&out[i*4] = o;
    }
}

// One prep launch:
//   blocks [0,2048):    cvt f32->bf16 of src/tar embeddings
//   blocks [2048,3072): transpose both weight tensors to bf16 WT[r][e][d]
//   blocks [3072,3328): initL — L[rb][t] = exp((dot(sn_r, tar_emb[b][t])
//                       + (1-tmask)*-1e10)/16), sn_r recomputed per block
//                       from f32 w_score (L2-resident). Independent of the
//                       other prep outputs -> safe in the same launch.
__global__ void prep_kernel(const float* __restrict__ src,
                            const float* __restrict__ tar,
                            const float* __restrict__ wsc,
                            const float* __restrict__ wem,
                            const float* __restrict__ none,
                            const float* __restrict__ tar_mask,
                            unsigned short* __restrict__ src_bf,
                            unsigned short* __restrict__ tar_bf,
                            unsigned short* __restrict__ wscT,
                            unsigned short* __restrict__ wembT,
                            float* __restrict__ L)
{
    int bid = blockIdx.x;
    if (bid < 2048) {
        const float* in = (bid < 1024) ? src : tar;
        unsigned short* out = (bid < 1024) ? src_bf : tar_bf;
        int i = ((bid & 1023) * 256 + threadIdx.x) * 4;
        float4 v = *(const float4*)(in + i);
        bf16x4 o;
        o[0] = (short)f2bf(v.x); o[1] = (short)f2bf(v.y);
        o[2] = (short)f2bf(v.z); o[3] = (short)f2bf(v.w);
        *(bf16x4*)(out + i) = o;
    } else if (bid < 3072) {
        __shared__ float tile[32][33];
        int b2 = bid - 2048;               // [0,1024): (e0,d0,z)
        int e0 = (b2 & 7) * 32, d0 = ((b2 >> 3) & 7) * 32, zz = b2 >> 6;
        int r = zz & 7;
        const float* w = (zz < 8) ? wsc : wem;
        unsigned short* wt = (zz < 8) ? wscT : wembT;
        int tx = threadIdx.x & 31, ty = threadIdx.x >> 5;  // ty 0..7
        #pragma unroll
        for (int k = 0; k < 32; k += 8)
            tile[ty + k][tx] = w[((size_t)r*DIMN + d0 + ty + k)*DIMN + e0 + tx];
        __syncthreads();
        #pragma unroll
        for (int k = 0; k < 32; k += 8)
            wt[((size_t)r*DIMN + e0 + ty + k)*DIMN + d0 + tx] = f2bf(tile[tx][ty + k]);
    } else {
        __shared__ float sn[DIMN];
        __shared__ float part[256];
        int b3 = bid - 3072;               // [0,256): (rb, tchunk)
        int rb = b3 & 63, tch = b3 >> 6;
        int r = rb >> 3, b = rb & 7;
        {   // per-block recompute of the none-node score row
            int e = threadIdx.x;
            float acc = 0.f;
            for (int d = 0; d < DIMN; ++d)
                acc += none[d] * wsc[((size_t)r*DIMN + d)*DIMN + e];
            sn[e] = acc;
        }
        __syncthreads();
        int tl = threadIdx.x & 127, half = threadIdx.x >> 7;
        int t = tch * 128 + tl;
        const float4* row = (const float4*)(tar + ((size_t)b*TN + t)*DIMN + half*128);
        float acc = 0.f;
        #pragma unroll
        for (int k = 0; k < 32; ++k) {
            float4 v = row[k];
            int e = half*128 + k*4;
            acc += v.x*sn[e] + v.y*sn[e+1] + v.z*sn[e+2] + v.w*sn[e+3];
        }
        part[threadIdx.x] = acc;
        __syncthreads();
        if (half == 0) {
            float s = part[tl] + part[tl + 128];
            float tm = tar_mask[b*TN + t];
            L[(size_t)rb*TN + t] = __expf((s + (1.f - tm) * -1e10f) * 0.0625f);
        }
    }
}

extern "C" void kernel_launch(void* const* d_in, const int* in_sizes, int n_in,
                              void* d_out, int out_size, void* d_ws, size_t ws_size,
                              hipStream_t stream)
{
    const float* src_emb  = (const float*)d_in[0];
    const float* tar_emb  = (const float*)d_in[1];
    const float* src_mask = (const float*)d_in[2];
    const float* tar_mask = (const float*)d_in[3];
    const float* w_score  = (const float*)d_in[4];
    const float* w_emb    = (const float*)d_in[5];
    const float* src_none = (const float*)d_in[6];
    // tar_none_node (d_in[7]) provably never reaches the output (t=512 sliced off)

    size_t off = 0;
    auto alloc = [&](size_t bytes) {
        char* q = (char*)d_ws + off;
        off += (bytes + 255) & ~(size_t)255;
        return q;
    };
    unsigned short* src_bf  = (unsigned short*)alloc((size_t)BN_*SN*DIMN*2);      // 2 MB
    unsigned short* tar_bf  = (unsigned short*)alloc((size_t)BN_*TN*DIMN*2);      // 2 MB
    unsigned short* wscT    = (unsigned short*)alloc((size_t)RELN*DIMN*DIMN*2);   // 1 MB
    unsigned short* wembT   = (unsigned short*)alloc((size_t)RELN*DIMN*DIMN*2);   // 1 MB
    unsigned short* scores  = (unsigned short*)alloc((size_t)RELN*BN_*SN*DIMN*2); // 16 MB
    unsigned short* wbuf    = (unsigned short*)alloc((size_t)RELN*BN_*SN*TN*2);   // 32 MB
    unsigned short* relT    = (unsigned short*)alloc((size_t)RELN*BN_*DIMN*TN*2); // 16 MB
    float*          outp4   = (float*)alloc((size_t)4*BN_*SN*DIMN*4);             // 16 MB
    float*          Lsum    = (float*)alloc((size_t)RELN*BN_*TN*4);               // 128 KB
    if (off > ws_size) return;  // fails loudly (output stays zero)

    // bf16 conversions + weight transposes + L init, one launch
    prep_kernel<<<3328, 256, 0, stream>>>(src_emb, tar_emb, w_score, w_emb,
                                          src_none, tar_mask,
                                          src_bf, tar_bf, wscT, wembT, Lsum);
    // GEMM1: scores (R, B*S, DIM) = src_bf (B*S, DIM) @ WscoreT[r]
    gemm_bt<1,32><<<dim3(32, 2, 8), 256, 0, stream>>>(src_bf, wscT, scores,
                                                      DIMN, DIMN, DIMN,
                                                      nullptr, nullptr, nullptr);
    // GEMM2: w~ (R*B, S, T) bf16 = exp(mask(scores @ tar^T)/16), L += colsums
    gemm_bt<2,32><<<dim3(4, 4, 64), 256, 0, stream>>>(scores, tar_bf, wbuf,
                                                      DIMN, DIMN, DIMN,
                                                      src_mask, tar_mask, Lsum);
    // GEMM3: relT (R,B,DIM,T) bf16 = (tar_bf @ WembT[r])/L, transposed store
    gemm_bt<3,32><<<dim3(32, 2, 8), 256, 0, stream>>>(tar_bf, wembT, relT,
                                                      DIMN, DIMN, DIMN,
                                                      nullptr, nullptr, Lsum);
    // GEMM4: split-K over (r-pair, t): outp4[z] = w~ @ relT^T partials
    //        (round-9 measured optimum: BK=64, 2 blocks/CU)
    gemm_bt<4,64><<<dim3(32, 2, 4), 256, 0, stream>>>(wbuf, relT, outp4,
                                                      1024, 0, 0,
                                                      nullptr, nullptr, nullptr);
    // out = (1/sqrt(8)) * sum_z outp4[z]
    reduce4_kernel<<<1024, 256, 0, stream>>>(outp4, (float*)d_out, BN_*SN*DIMN/4);
}

// Round 13
// 83.856 us; speedup vs baseline: 1.1076x; 1.1076x over previous
//
#include <hip/hip_runtime.h>

#define RELN 8
#define DIMN 256
#define BN_  8
#define SN   512
#define TN   512

typedef __attribute__((ext_vector_type(8))) short bf16x8;   // 8 bf16 payloads
typedef __attribute__((ext_vector_type(4))) short bf16x4;
typedef __attribute__((ext_vector_type(4))) float f32x4;

__device__ __forceinline__ unsigned short f2bf(float f) {
    union { float f; unsigned u; } x; x.f = f;
    return (unsigned short)((x.u + 0x7FFFu + ((x.u >> 16) & 1u)) >> 16);  // RNE
}
__device__ __forceinline__ float bf2f(unsigned short h) {
    union { unsigned u; float f; } x; x.u = (unsigned)h << 16; return x.f;
}

// ---------------------------------------------------------------------------
// bf16 MFMA GEMM, B^T layout (A: MxK row-major, B: NxK row-major).
// 128x128 tile, template BK, 4 waves x 64x64 quadrant (frags of 16x16x32).
// 2-phase double-buffered staging; global_load_lds width=16, linear LDS.
// MODE 1/2/3: BK=32 -> LDS 32 KB -> 4 blocks/CU co-residency (per-step
// vmcnt(0)+barrier drain hidden by other resident blocks' MFMA, m114).
// MODE 4:     BK=64, 2 blocks/CU (K=1024 split-K; BK=32 measured worse).
// Measured config notes (rounds 9-12): bounds-5 collapses occupancy (160KB
// has no slack); XCD swizzle out-of-regime (L3-resident data); this exact
// configuration is the measured optimum of the structure (84.2 us).
// MODE 1: scores = src_bf @ WscoreT[r]                     (z=r,      bf16)
// MODE 2: w~ = exp(mask(scores @ tar_bf^T)/16)             (z=r*8+b,  bf16)
//         + column-sum atomicAdd into L[rb][t]  (no-max-sub softmax: logits
//         bounded ~|6| by construction, exp never overflows f32)
// MODE 3: relT = (tar_bf @ WembT[r]) / L[rb][t], transposed 2-pass LDS
//         bounce (pitch 136, conflict-free) -> coalesced 16B stores
// MODE 4: split-K over fused (r,t): outp4[z] = sum w~*relT partials
//         (z=0..3, K=1024, f32 direct stores)
// ---------------------------------------------------------------------------
#define TBN 128
#define BP12 128   // MODE1/2 bounce pitch (shorts): 128x128 = 32 KB = Sh size
#define BP3  136   // MODE3 transposed bounce pitch: 2-way max on both sides

template<int MODE, int BK>
__global__ __launch_bounds__(256, (MODE == 4 ? 2 : 4))
void gemm_bt(const unsigned short* __restrict__ A,
             const unsigned short* __restrict__ B,
             void* __restrict__ C, int K,
             int lda, int ldb,
             const float* __restrict__ msrc,
             const float* __restrict__ mtar,
             float* __restrict__ Lsum)
{
    __shared__ unsigned short Sh[2][(128 + TBN) * BK];
    const int tid  = threadIdx.x;
    const int lane = tid & 63;
    const int wv   = tid >> 6;
    const int wr   = (wv >> 1) * 64;
    const int wc   = (wv & 1) * 64;
    const int m0   = blockIdx.x * 128;
    const int n0   = blockIdx.y * TBN;
    const int z    = blockIdx.z;
    const int bblk = m0 >> 9;        // MODE 2/3/4: batch b of this m-tile
    const int rz   = z * 2;          // MODE 4: first r of this z's pair

    const unsigned short* Ab = A;
    const unsigned short* Bb = B;
    if (MODE == 1)      { Bb += (size_t)z * DIMN * DIMN; }
    else if (MODE == 2) { Ab += (size_t)z * SN * DIMN; Bb += (size_t)(z & 7) * TN * DIMN; }
    else if (MODE == 3) { Bb += (size_t)z * DIMN * DIMN; }

    // stage one 128xBK A-tile + 128xBK B-tile into Sh[buf]; LDS dest linear
    // (wave base + lane*16B HW scatter), global src matches elementwise.
    constexpr int CPR = BK / 8;            // 16B chunks per row
    constexpr int NP  = 128 * CPR / 256;   // passes per operand
    auto stage = [&](int buf, int kt) {
        unsigned short* Abase = Sh[buf];
        unsigned short* Bbase = Sh[buf] + 128 * BK;
        #pragma unroll
        for (int p = 0; p < NP; ++p) {
            int idx8 = p * 256 + tid;
            int row  = idx8 / CPR;
            int col  = (idx8 % CPR) * 8;
            size_t aoff, boff;
            if (MODE == 4) {
                int r = rz + (kt >> 9);        // fused k = r_local*512 + t
                int t = (kt & 511) + col;      // BK | 512: never crosses r
                aoff = ((size_t)((r*BN_ + bblk)*SN + ((m0 + row) & 511)))*TN + t;
                boff = ((size_t)((r*BN_ + bblk)*DIMN + (n0 + row)))*TN + t;
            } else {
                aoff = (size_t)(m0 + row)*lda + kt + col;
                boff = (size_t)(n0 + row)*ldb + kt + col;
            }
            __builtin_amdgcn_global_load_lds(
                (const __attribute__((address_space(1))) unsigned int*)&Ab[aoff],
                (__attribute__((address_space(3))) unsigned int*)
                    &Abase[p*2048 + wv*512], 16, 0, 0);
            __builtin_amdgcn_global_load_lds(
                (const __attribute__((address_space(1))) unsigned int*)&Bb[boff],
                (__attribute__((address_space(3))) unsigned int*)
                    &Bbase[p*2048 + wv*512], 16, 0, 0);
        }
    };

    f32x4 acc[4][4] = {};
    const int nsteps = K / BK;
    stage(0, 0);
    int cur = 0;
    for (int s = 0; s < nsteps; ++s) {
        // drains vmcnt(0): buf[cur] ready; all waves done reading buf[cur^1]
        __syncthreads();
        if (s + 1 < nsteps) stage(cur ^ 1, (s + 1) * BK);   // in flight over MFMA
        const unsigned short* As = Sh[cur];
        const unsigned short* Bs = Sh[cur] + 128 * BK;
        #pragma unroll
        for (int kk = 0; kk < BK / 32; ++kk) {
            const int ko = kk*32 + (lane >> 4) * 8;
            bf16x8 af[4], bfv[4];
            #pragma unroll
            for (int i = 0; i < 4; ++i)
                af[i] = *(const bf16x8*)&As[(wr + i*16 + (lane & 15))*BK + ko];
            #pragma unroll
            for (int j = 0; j < 4; ++j)
                bfv[j] = *(const bf16x8*)&Bs[(wc + j*16 + (lane & 15))*BK + ko];
            #pragma unroll
            for (int i = 0; i < 4; ++i) {
                #pragma unroll
                for (int j = 0; j < 4; ++j)
                    acc[i][j] = __builtin_amdgcn_mfma_f32_16x16x32_bf16(af[i], bfv[j], acc[i][j], 0, 0, 0);
            }
        }
        cur ^= 1;
    }

    // C/D frag mapping (m89-verified): col = lane&15, row = (lane>>4)*4 + reg
    const int r0 = (lane >> 4) * 4;
    const int cl = lane & 15;
    unsigned short* tile = &Sh[0][0];   // bounce space (32 KB at BK=32)

    if (MODE == 2) {
        unsigned short* Cp = (unsigned short*)C + (size_t)z * SN * TN;
        const int b = z & 7;
        float tm[4];
        #pragma unroll
        for (int j = 0; j < 4; ++j) tm[j] = mtar[b*TN + n0 + wc + j*16 + cl];
        float colsum[4] = {0.f, 0.f, 0.f, 0.f};
        __syncthreads();   // staging fully consumed; safe to reuse Sh as bounce
        #pragma unroll
        for (int i = 0; i < 4; ++i) {
            int rowl = wr + i*16 + r0;
            float sm[4];
            #pragma unroll
            for (int q = 0; q < 4; ++q) sm[q] = msrc[b*SN + m0 + rowl + q];
            #pragma unroll
            for (int j = 0; j < 4; ++j) {
                int coll = wc + j*16 + cl;
                #pragma unroll
                for (int q = 0; q < 4; ++q) {
                    float v = (acc[i][j][q] + (1.f - sm[q]*tm[j]) * -1e10f) * 0.0625f;
                    float e = __expf(v);
                    tile[(rowl + q)*BP12 + coll] = f2bf(e);
                    colsum[j] += e;
                }
            }
        }
        // reduce the 4 row-groups (lane>>4) holding the same column, then atomic
        #pragma unroll
        for (int j = 0; j < 4; ++j) {
            float v = colsum[j];
            v += __shfl_xor(v, 16, 64);
            v += __shfl_xor(v, 32, 64);
            if (lane < 16)
                atomicAdd(&Lsum[(size_t)z*TN + n0 + wc + j*16 + cl], v);
        }
        __syncthreads();
        #pragma unroll
        for (int p = 0; p < 8; ++p) {      // 128 rows x 16 chunks of 16 B
            int chunk = p * 256 + tid;
            int row = chunk >> 4, col = (chunk & 15) * 8;
            bf16x8 v = *(const bf16x8*)&tile[row*BP12 + col];
            *(bf16x8*)&Cp[(size_t)(m0 + row)*TN + n0 + col] = v;
        }
    } else if (MODE == 1) {
        unsigned short* Cp = (unsigned short*)C + (size_t)z * (BN_*SN) * DIMN;
        __syncthreads();
        #pragma unroll
        for (int i = 0; i < 4; ++i) {
            int rowl = wr + i*16 + r0;
            #pragma unroll
            for (int j = 0; j < 4; ++j) {
                int coll = wc + j*16 + cl;
                #pragma unroll
                for (int q = 0; q < 4; ++q)
                    tile[(rowl + q)*BP12 + coll] = f2bf(acc[i][j][q]);
            }
        }
        __syncthreads();
        #pragma unroll
        for (int p = 0; p < 8; ++p) {
            int chunk = p * 256 + tid;
            int row = chunk >> 4, col = (chunk & 15) * 8;
            bf16x8 v = *(const bf16x8*)&tile[row*BP12 + col];
            *(bf16x8*)&Cp[(size_t)(m0 + row)*DIMN + n0 + col] = v;
        }
    } else if (MODE == 3) {
        // transposed 2-pass bounce: tile[e_local][t_local] (64 e-rows per
        // pass, pitch 136 -> 2-way max) then coalesced 16B stores of
        // relT[(z*8+b)*256 + e][t]
        unsigned short* Cp = (unsigned short*)C;
        const int t_base = m0 & 511;
        #pragma unroll
        for (int h = 0; h < 2; ++h) {
            __syncthreads();
            if ((wv & 1) == h) {           // waves owning e in [h*64,(h+1)*64)
                #pragma unroll
                for (int i = 0; i < 4; ++i) {
                    int tl0  = wr + i*16 + r0;          // 4 consecutive t (q)
                    float4 Lv = *(const float4*)
                        &Lsum[((size_t)(z*BN_ + bblk))*TN + t_base + tl0];
                    float inv0 = 1.f / Lv.x, inv1 = 1.f / Lv.y,
                          inv2 = 1.f / Lv.z, inv3 = 1.f / Lv.w;
                    #pragma unroll
                    for (int j = 0; j < 4; ++j) {
                        int el = wc + j*16 + cl - h*64;
                        bf16x4 v;
                        v[0] = (short)f2bf(acc[i][j][0] * inv0);
                        v[1] = (short)f2bf(acc[i][j][1] * inv1);
                        v[2] = (short)f2bf(acc[i][j][2] * inv2);
                        v[3] = (short)f2bf(acc[i][j][3] * inv3);
                        *(bf16x4*)&tile[el*BP3 + tl0] = v;
                    }
                }
            }
            __syncthreads();
            #pragma unroll
            for (int p = 0; p < 4; ++p) {  // 64 e-rows x 16 chunks of 16 B
                int chunk = p * 256 + tid;
                int er = chunk >> 4, tc = (chunk & 15) * 8;
                bf16x8 v = *(const bf16x8*)&tile[er*BP3 + tc];
                *(bf16x8*)&Cp[((size_t)(z*BN_ + bblk)*DIMN + n0 + h*64 + er)*TN
                              + t_base + tc] = v;
            }
        }
    } else {
        // per-z partials, plain stores (16 lanes x 4B = 64B contiguous)
        float* Cp = (float*)C + (size_t)z * (BN_*SN) * DIMN;
        #pragma unroll
        for (int i = 0; i < 4; ++i) {
            int row = m0 + wr + i*16 + r0;
            #pragma unroll
            for (int j = 0; j < 4; ++j) {
                int col = n0 + wc + j*16 + cl;
                #pragma unroll
                for (int q = 0; q < 4; ++q)
                    Cp[(size_t)(row + q)*DIMN + col] = acc[i][j][q];
            }
        }
    }
}

// out = (1/sqrt(8)) * sum_{z<4} part[z]  (streaming, fully overwrites d_out)
__global__ void reduce4_kernel(const float* __restrict__ part,
                               float* __restrict__ out, int n4)
{
    int i = blockIdx.x * 256 + threadIdx.x;
    if (i < n4) {
        float4 s = {0.f, 0.f, 0.f, 0.f};
        #pragma unroll
        for (int r = 0; r < 4; ++r) {
            float4 v = *(const float4*)&part[(size_t)r*(BN_*SN*DIMN) + i*4];
            s.x += v.x; s.y += v.y; s.z += v.z; s.w += v.w;
        }
        const float k = 0.35355339059327373f;
        float4 o = {s.x*k, s.y*k, s.z*k, s.w*k};
        *(float4*)&out[i*4] = o;
    }
}

// One prep launch: blocks [0,2048) cvt f32->bf16 of src/tar embeddings;
// blocks [2048,3072) transpose both weight tensors to bf16 WT[r][e][d].
__global__ void prep_kernel(const float* __restrict__ src,
                            const float* __restrict__ tar,
                            const float* __restrict__ wsc,
                            const float* __restrict__ wem,
                            unsigned short* __restrict__ src_bf,
                            unsigned short* __restrict__ tar_bf,
                            unsigned short* __restrict__ wscT,
                            unsigned short* __restrict__ wembT)
{
    int bid = blockIdx.x;
    if (bid < 2048) {
        const float* in = (bid < 1024) ? src : tar;
        unsigned short* out = (bid < 1024) ? src_bf : tar_bf;
        int i = ((bid & 1023) * 256 + threadIdx.x) * 4;
        float4 v = *(const float4*)(in + i);
        bf16x4 o;
        o[0] = (short)f2bf(v.x); o[1] = (short)f2bf(v.y);
        o[2] = (short)f2bf(v.z); o[3] = (short)f2bf(v.w);
        *(bf16x4*)(out + i) = o;
    } else {
        __shared__ float tile[32][33];
        int b2 = bid - 2048;               // [0,1024): (e0,d0,z)
        int e0 = (b2 & 7) * 32, d0 = ((b2 >> 3) & 7) * 32, zz = b2 >> 6;
        int r = zz & 7;
        const float* w = (zz < 8) ? wsc : wem;
        unsigned short* wt = (zz < 8) ? wscT : wembT;
        int tx = threadIdx.x & 31, ty = threadIdx.x >> 5;  // ty 0..7
        #pragma unroll
        for (int k = 0; k < 32; k += 8)
            tile[ty + k][tx] = w[((size_t)r*DIMN + d0 + ty + k)*DIMN + e0 + tx];
        __syncthreads();
        #pragma unroll
        for (int k = 0; k < 32; k += 8)
            wt[((size_t)r*DIMN + e0 + ty + k)*DIMN + d0 + tx] = f2bf(tile[tx][ty + k]);
    }
}

// L[rb][t] = exp((dot(sn_r, tar_bf[b][t]) + (1-tmask)*-1e10)/16), where
// sn_r[e] = sum_d src_none[d]*Wscore[r][d][e] is recomputed per block
// (w_score is 2 MB, L2-resident across the 256 blocks).
__global__ void initL_kernel(const float* __restrict__ wsc,
                             const float* __restrict__ none,
                             const unsigned short* __restrict__ tar_bf,
                             const float* __restrict__ tar_mask,
                             float* __restrict__ L)
{
    __shared__ float sn[DIMN];
    __shared__ float part[256];
    int rb = blockIdx.x, r = rb >> 3, b = rb & 7;
    {   // phase A: per-block recompute of the none-node score row
        int e = threadIdx.x;
        float acc = 0.f;
        for (int d = 0; d < DIMN; ++d)
            acc += none[d] * wsc[((size_t)r*DIMN + d)*DIMN + e];
        sn[e] = acc;
    }
    __syncthreads();
    int tl = threadIdx.x & 127, half = threadIdx.x >> 7;
    int t = blockIdx.y * 128 + tl;
    const unsigned short* rowp = tar_bf + ((size_t)b*TN + t)*DIMN + half*128;
    float acc = 0.f;
    #pragma unroll
    for (int k = 0; k < 16; ++k) {
        bf16x8 v = *(const bf16x8*)&rowp[k*8];
        #pragma unroll
        for (int j = 0; j < 8; ++j)
            acc += bf2f((unsigned short)v[j]) * sn[half*128 + k*8 + j];
    }
    part[threadIdx.x] = acc;
    __syncthreads();
    if (half == 0) {
        float s = part[tl] + part[tl + 128];
        float tm = tar_mask[b*TN + t];
        L[(size_t)rb*TN + t] = __expf((s + (1.f - tm) * -1e10f) * 0.0625f);
    }
}

extern "C" void kernel_launch(void* const* d_in, const int* in_sizes, int n_in,
                              void* d_out, int out_size, void* d_ws, size_t ws_size,
                              hipStream_t stream)
{
    const float* src_emb  = (const float*)d_in[0];
    const float* tar_emb  = (const float*)d_in[1];
    const float* src_mask = (const float*)d_in[2];
    const float* tar_mask = (const float*)d_in[3];
    const float* w_score  = (const float*)d_in[4];
    const float* w_emb    = (const float*)d_in[5];
    const float* src_none = (const float*)d_in[6];
    // tar_none_node (d_in[7]) provably never reaches the output (t=512 sliced off)

    size_t off = 0;
    auto alloc = [&](size_t bytes) {
        char* q = (char*)d_ws + off;
        off += (bytes + 255) & ~(size_t)255;
        return q;
    };
    unsigned short* src_bf  = (unsigned short*)alloc((size_t)BN_*SN*DIMN*2);      // 2 MB
    unsigned short* tar_bf  = (unsigned short*)alloc((size_t)BN_*TN*DIMN*2);      // 2 MB
    unsigned short* wscT    = (unsigned short*)alloc((size_t)RELN*DIMN*DIMN*2);   // 1 MB
    unsigned short* wembT   = (unsigned short*)alloc((size_t)RELN*DIMN*DIMN*2);   // 1 MB
    unsigned short* scores  = (unsigned short*)alloc((size_t)RELN*BN_*SN*DIMN*2); // 16 MB
    unsigned short* wbuf    = (unsigned short*)alloc((size_t)RELN*BN_*SN*TN*2);   // 32 MB
    unsigned short* relT    = (unsigned short*)alloc((size_t)RELN*BN_*DIMN*TN*2); // 16 MB
    float*          outp4   = (float*)alloc((size_t)4*BN_*SN*DIMN*4);             // 16 MB
    float*          Lsum    = (float*)alloc((size_t)RELN*BN_*TN*4);               // 128 KB
    if (off > ws_size) return;  // fails loudly (output stays zero)

    // bf16 conversions + weight transposes, one launch
    prep_kernel<<<3072, 256, 0, stream>>>(src_emb, tar_emb, w_score, w_emb,
                                          src_bf, tar_bf, wscT, wembT);
    // L seeded with the none-node row's exp (the only way src_none affects out)
    initL_kernel<<<dim3(64, 4), 256, 0, stream>>>(w_score, src_none, tar_bf,
                                                  tar_mask, Lsum);
    // GEMM1: scores (R, B*S, DIM) = src_bf (B*S, DIM) @ WscoreT[r]
    gemm_bt<1,32><<<dim3(32, 2, 8), 256, 0, stream>>>(src_bf, wscT, scores,
                                                      DIMN, DIMN, DIMN,
                                                      nullptr, nullptr, nullptr);
    // GEMM2: w~ (R*B, S, T) bf16 = exp(mask(scores @ tar^T)/16), L += colsums
    gemm_bt<2,32><<<dim3(4, 4, 64), 256, 0, stream>>>(scores, tar_bf, wbuf,
                                                      DIMN, DIMN, DIMN,
                                                      src_mask, tar_mask, Lsum);
    // GEMM3: relT (R,B,DIM,T) bf16 = (tar_bf @ WembT[r])/L, transposed store
    gemm_bt<3,32><<<dim3(32, 2, 8), 256, 0, stream>>>(tar_bf, wembT, relT,
                                                      DIMN, DIMN, DIMN,
                                                      nullptr, nullptr, Lsum);
    // GEMM4: split-K over (r-pair, t): outp4[z] = w~ @ relT^T partials
    //        (measured optimum: BK=64, 2 blocks/CU)
    gemm_bt<4,64><<<dim3(32, 2, 4), 256, 0, stream>>>(wbuf, relT, outp4,
                                                      1024, 0, 0,
                                                      nullptr, nullptr, nullptr);
    // out = (1/sqrt(8)) * sum_z outp4[z]
    reduce4_kernel<<<1024, 256, 0, stream>>>(outp4, (float*)d_out, BN_*SN*DIMN/4);
}